// Round 2
// baseline (6363.118 us; speedup 1.0000x reference)
//
#include <hip/hip_runtime.h>

// Problem constants
#define B_    64
#define T_    512
#define KDIM  1024
#define HID_  1024

// R14 geometry: R12 datapath (64x64 tile, 4x4/thread, b128 reads) with
// BK=16 thin slices to shrink LDS to 20.7 KB -> 5-6 blocks/CU.
#define BM 64     // t-chunk per block iteration (8 chunks)
#define BN 64     // h-tile per block
#define BK 16     // one numpy 16-k block per slice
#define LDA 20    // padded LDS row: 16 + 4 floats (80 B, 16B-aligned rows)
#define NSL 512   // total slices = (T_/BM)*(KDIM/BK)
#define SPC 64    // slices per chunk = KDIM/BK
#define BOFF 1280   // Bs offset within a buffer (64*20 floats)
#define BUFSZ 2560  // per-buffer floats: A 1280 + B 1280
#define ISMLD 65    // Ism [32][65] = 2080 f, aliased inside AB1 (2560 f)
// total smem floats = 2*2560 + 64 = 5184 (20736 B)

// f32 correctly rounded from python float math.exp(-1.0/20.0)
#define ALPHA_F 0.95122942450071400909f

typedef float v4f __attribute__((ext_vector_type(4)));
typedef float v2f __attribute__((ext_vector_type(2)));

// Bit-faithful replication of the harness numpy f32 reference: per output
// element 4 f32 accumulator lanes (lane l sums k = l mod 4), 16-k blocks
// ascending (slices ascending), q descending within block, mul/add separately
// rounded (no FMA), hadd tree (l0+l1)+(l2+l3), one f32 bias add; f32 scan.
// Chain byte-identical to R6..R13 (all PASSED).
//
// R14 vs R13 (1.589 ms) / R12 (1.505 ms): R13 halved LDS BYTES at constant
// LDS instr count and regressed with VALUBusy down (72->64%) -> R12 is not
// LDS-bandwidth-bound; the ~420 us idle is per-slice barrier-drain latency
// that 16 waves/CU can't fully cover. R14 attacks occupancy only: BK 32->16
// halves each buffer (A/B 64x20 f), Ism shrinks to a 32-row half-chunk
// buffer aliased inside AB1 (scan runs twice per chunk), staging regs drop
// 24->8. LDS 37.4 KB -> 20.7 KB (7 blocks by LDS), VGPR ~88-100 -> 5-6
// blocks/CU = 20-24 waves/CU. Datapath, read widths, and rounding chain are
// unchanged from R12.
__global__ __launch_bounds__(256, 5) void snn_np_occ(
    const float* __restrict__ x,     // [B,T,K] f32
    const float* __restrict__ W,     // [H,K] f32
    const float* __restrict__ bias,  // [H] f32
    float* __restrict__ spikes,      // [B,T,H] f32 out
    float* __restrict__ memf)        // [B,H] f32 out
{
#pragma clang fp contract(off)       // numpy SSE path has no FMA: mul+add only
    __shared__ float smem[5184];     // 20736 B total
    float* const AB0 = smem;             // As0 @0, Bs0 @1280
    float* const AB1 = smem + BUFSZ;     // As1, Bs1
    float* const Ism = AB1;              // [32][65] — aliases AB1 (disjoint phases)
    float* const bsh = smem + 2 * BUFSZ; // [64]

    const int tid = threadIdx.x;
    const int bb  = blockIdx.x;          // batch index
    const int h0  = blockIdx.y * BN;     // h tile origin

    const int tx = tid & 15;             // h micro-index (4 cols, stride 16)
    const int ty = tid >> 4;             // t micro-index (4 rows, stride 16)

    const int srow = tid >> 2;           // staging row 0..63
    const int scol = (tid & 3) << 2;     // staging col 0,4,8,12

    const float* xb = x + (size_t)bb * T_ * KDIM;
    const float* Wb = W + (size_t)h0 * KDIM;

    if (tid < BN) bsh[tid] = bias[h0 + tid];

    float mem = 0.0f;                    // threads 0..63 carry h = h0+tid

    // ---- prologue: slice 0 -> AB0; slice 1 -> regs ----
    float4 pa, pw;
    pa = *(const float4*)&xb[(size_t)srow * KDIM + scol];
    pw = *(const float4*)&Wb[(size_t)srow * KDIM + scol];
    *(float4*)&AB0[srow * LDA + scol]        = pa;
    *(float4*)&AB0[BOFF + srow * LDA + scol] = pw;
    pa = *(const float4*)&xb[(size_t)srow * KDIM + 16 + scol];
    pw = *(const float4*)&Wb[(size_t)srow * KDIM + 16 + scol];
    __syncthreads();                     // AB0 + bsh visible

    for (int c = 0; c < T_ / BM; ++c) {
        // numpy 4-lane accumulators, lane-paired: p01 = lanes {0,1}, p23 = {2,3}
        v2f p01[4][4], p23[4][4];
#pragma unroll
        for (int j = 0; j < 4; ++j)
#pragma unroll
            for (int i = 0; i < 4; ++i) {
                p01[j][i] = (v2f)(0.0f);
                p23[j][i] = (v2f)(0.0f);
            }

        for (int s = 0; s < SPC; ++s) {
            const int g = c * SPC + s;
            float* const cb = (g & 1) ? AB1 : AB0;   // compute buffer (slice g)
            float* const nb = (g & 1) ? AB0 : AB1;   // commit target (slice g+1)

            // 1) commit regs (slice g+1) into nb — overlapped with compute;
            //    nb's old readers finished before the previous barrier.
            if (g + 1 < NSL) {
                *(float4*)&nb[srow * LDA + scol]        = pa;
                *(float4*)&nb[BOFF + srow * LDA + scol] = pw;
            }
            // 2) issue slice g+2 loads; a whole compute phase to land.
            if (g + 2 < NSL) {
                const int gs  = g + 2;
                const int nt0 = (gs >> 6) * BM;
                const int nk  = (gs & 63) << 4;
                pa = *(const float4*)&xb[(size_t)(nt0 + srow) * KDIM + nk + scol];
                pw = *(const float4*)&Wb[(size_t)srow * KDIM + nk + scol];
            }
            // 3) compute slice g: one numpy 16-k block; q=3..0 —
            // per-lane acc += a[4q+l]*b[4q+l], mul then add: bitwise equal to
            // numpy's chained a0b0+(a1b1+(a2b2+(a3b3+acc)))
#pragma unroll
            for (int q = 3; q >= 0; --q) {
                const int qc = q << 2;
                v2f a01[4], a23[4], b01[4], b23[4];
#pragma unroll
                for (int j = 0; j < 4; ++j) {
                    const v4f a = *(const v4f*)&cb[(ty + 16 * j) * LDA + qc];
                    a01[j] = a.xy; a23[j] = a.zw;
                }
#pragma unroll
                for (int i = 0; i < 4; ++i) {
                    const v4f b = *(const v4f*)&cb[BOFF + (tx + 16 * i) * LDA + qc];
                    b01[i] = b.xy; b23[i] = b.zw;
                }
#pragma unroll
                for (int j = 0; j < 4; ++j)
#pragma unroll
                    for (int i = 0; i < 4; ++i) {
                        const v2f m01 = a01[j] * b01[i];   // packed rounded muls
                        const v2f m23 = a23[j] * b23[i];
                        p01[j][i] = p01[j][i] + m01;       // packed rounded adds
                        p23[j][i] = p23[j][i] + m23;
                    }
            }
            __syncthreads();   // slice g reads done; slice g+1 commit visible
        }

        // epilogue in two 32-row halves (Ism = [32][65] aliases AB1).
        // Chunk-final slice (g = c*64+63) is odd: computed from AB1, committed
        // next-chunk slice 0 into AB0 — AB1 is free; AB0 survives the scans.
        // Next chunk's first commit targets AB1, after the last scan barrier.
#pragma unroll
        for (int half = 0; half < 2; ++half) {
#pragma unroll
            for (int j = 0; j < 2; ++j) {
                const int jj = half * 2 + j;
#pragma unroll
                for (int i = 0; i < 4; ++i) {
                    const float s01 = p01[jj][i].x + p01[jj][i].y;
                    const float s23 = p23[jj][i].x + p23[jj][i].y;
                    Ism[(ty + 16 * j) * ISMLD + (tx + 16 * i)] =
                        (s01 + s23) + bsh[tx + 16 * i];    // (l0+l1)+(l2+l3)+b
                }
            }
            __syncthreads();

            // f32 LIF scan over this half-chunk; one thread per h.
            if (tid < BN) {
                const size_t srow0 =
                    ((size_t)(bb * T_ + c * BM + half * 32)) * HID_ + h0 + tid;
#pragma unroll 4
                for (int t = 0; t < 32; ++t) {
                    const float It = Ism[t * ISMLD + tid];
                    const float am = ALPHA_F * mem;   // rounded mul
                    mem = am + It;                    // rounded add
                    const bool fire = (mem >= 1.0f);
                    spikes[srow0 + (size_t)t * HID_] = fire ? 1.0f : 0.0f;
                    if (fire) mem = 0.0f;
                }
            }
            __syncthreads();   // scan's Ism reads done before Ism rewrite /
                               // next chunk's iter-0 commit into AB1
        }
    }

    if (tid < BN) memf[(size_t)bb * HID_ + h0 + tid] = mem;
}

extern "C" void kernel_launch(void* const* d_in, const int* in_sizes, int n_in,
                              void* d_out, int out_size, void* d_ws, size_t ws_size,
                              hipStream_t stream) {
    const float* x    = (const float*)d_in[0];   // [B,T,K] f32
    const float* W    = (const float*)d_in[1];   // [H,K] f32
    const float* bias = (const float*)d_in[2];   // [H] f32
    float* out    = (float*)d_out;
    float* spikes = out;                          // [B,T,H]
    float* memf   = out + (size_t)B_ * T_ * HID_; // [B,H]

    dim3 grid(B_, HID_ / BN);   // 64 x 16 = 1024 blocks
    snn_np_occ<<<grid, dim3(256), 0, stream>>>(x, W, bias, spikes, memf);
}